// Round 6
// baseline (1553.120 us; speedup 1.0000x reference)
//
#include <hip/hip_runtime.h>
#include <math.h>

// Problem constants (from reference)
#define Nn   100000
#define Ee   300000
#define FIN  128
#define Hdim 256
#define Ncls 40
#define Lnum 6
#define SCAN_B 98   // ceil(Nn/1024)

typedef __attribute__((ext_vector_type(8))) short bf16x8;
typedef __attribute__((ext_vector_type(4))) float f32x4;

// ---------------- bf16 helpers (storage bf16, compute fp32) ----------------
__device__ __forceinline__ float bf2f(unsigned int u16) {
    unsigned int x = u16 << 16;
    return __builtin_bit_cast(float, x);
}
__device__ __forceinline__ unsigned short f2bf(float f) {
    unsigned int x = __builtin_bit_cast(unsigned int, f);
    x = (x + 0x7FFFu + ((x >> 16) & 1u)) >> 16;   // round-nearest-even
    return (unsigned short)x;
}
__device__ __forceinline__ void unpack2(unsigned int u, float& lo, float& hi) {
    lo = __builtin_bit_cast(float, u << 16);
    hi = __builtin_bit_cast(float, u & 0xFFFF0000u);
}
__device__ __forceinline__ unsigned int pack2(float a, float b) {
    return (unsigned int)f2bf(a) | ((unsigned int)f2bf(b) << 16);
}

// ---------------------------------------------------------------------------
// Graph preprocessing
// ---------------------------------------------------------------------------
__global__ void count_edges(const int* __restrict__ ei, int* __restrict__ cnt) {
    int e = blockIdx.x * blockDim.x + threadIdx.x;
    if (e < Ee) atomicAdd(&cnt[ei[Ee + e]], 1);   // row 1 of edge_index = dst
}

__global__ void scan_block(const int* __restrict__ cnt, int* __restrict__ iscan,
                           int* __restrict__ btot) {
    __shared__ int buf[1024];
    int t = threadIdx.x;
    int g = blockIdx.x * 1024 + t;
    int v = (g < Nn) ? cnt[g] : 0;
    buf[t] = v; __syncthreads();
    for (int off = 1; off < 1024; off <<= 1) {
        int x = buf[t];
        int a = (t >= off) ? buf[t - off] : 0;
        __syncthreads();
        buf[t] = x + a;
        __syncthreads();
    }
    if (g < Nn) iscan[g] = buf[t];
    if (t == 1023) btot[blockIdx.x] = buf[1023];
}

__global__ void scan_tops(const int* __restrict__ btot, int* __restrict__ bpref) {
    __shared__ int b[128];
    int t = threadIdx.x;
    int v = (t < SCAN_B) ? btot[t] : 0;
    b[t] = v; __syncthreads();
    for (int off = 1; off < 128; off <<= 1) {
        int x = b[t];
        int a = (t >= off) ? b[t - off] : 0;
        __syncthreads();
        b[t] = x + a;
        __syncthreads();
    }
    if (t < SCAN_B) bpref[t] = b[t] - v;   // exclusive
}

__global__ void scan_final(const int* __restrict__ cnt, const int* __restrict__ iscan,
                           const int* __restrict__ bpref, int* __restrict__ offs,
                           float* __restrict__ dinvp) {
    int g = blockIdx.x * 1024 + threadIdx.x;
    if (g < Nn) {
        int c = cnt[g];
        offs[g] = bpref[blockIdx.x] + iscan[g] - c;
        dinvp[g] = rsqrtf((float)(c + 1));    // deg = in-deg + self-loop
    }
    if (g == 0) offs[Nn] = Ee;
}

__global__ void fill_csr(const int* __restrict__ ei, const int* __restrict__ offs,
                         int* __restrict__ cur, const float* __restrict__ dinvp,
                         int* __restrict__ esrc, float* __restrict__ ew) {
    int e = blockIdx.x * blockDim.x + threadIdx.x;
    if (e >= Ee) return;
    int s = ei[e], d = ei[Ee + e];
    int p = offs[d] + atomicAdd(&cur[d], 1);
    esrc[p] = s;
    ew[p] = dinvp[s];
}

// ---------------------------------------------------------------------------
// All weight prep in ONE dispatch (blockIdx ranges)
// ---------------------------------------------------------------------------
__global__ void prep_weights(const float* __restrict__ conv_w, const float* __restrict__ w_in,
                             const float* __restrict__ out_w,
                             unsigned short* __restrict__ Whi, unsigned short* __restrict__ Wlo,
                             unsigned short* __restrict__ Fhi, unsigned short* __restrict__ Flo,
                             unsigned short* __restrict__ Whd, unsigned short* __restrict__ Wld) {
    int b = blockIdx.x, t = threadIdx.x;
    if (b < 1536) {
        int id = b * 256 + t;                    // [0, 393216)
        int l = id >> 16, k = (id >> 8) & 255, n = id & 255;
        float w = conv_w[id];
        unsigned short hi = f2bf(w);
        unsigned short lo = f2bf(w - bf2f(hi));
        Whi[l * 65536 + n * 256 + k] = hi;
        Wlo[l * 65536 + n * 256 + k] = lo;
    } else if (b < 1664) {
        int id = (b - 1536) * 256 + t;           // [0, 32768)
        int k = id >> 8, n = id & 255;
        float w = w_in[id];
        unsigned short hi = f2bf(w);
        unsigned short lo = f2bf(w - bf2f(hi));
        Fhi[n * FIN + k] = hi;
        Flo[n * FIN + k] = lo;
    } else {
        int id = (b - 1664) * 256 + t;           // [0, 12288)
        int c = id >> 8, k = id & 255;
        float w = (c < Ncls) ? out_w[k * Ncls + c] : 0.f;
        unsigned short hi = f2bf(w);
        unsigned short lo = f2bf(w - bf2f(hi));
        Whd[c * 256 + k] = hi;
        Wld[c * 256 + k] = lo;
    }
}

// x fp32 -> bf16 (8 elems/thread)
__global__ void cvt_bf16(const float* __restrict__ src, unsigned short* __restrict__ dst, int n8) {
    int i = blockIdx.x * blockDim.x + threadIdx.x;
    if (i >= n8) return;
    float4 a = ((const float4*)src)[i * 2];
    float4 b = ((const float4*)src)[i * 2 + 1];
    uint4 o;
    o.x = pack2(a.x, a.y); o.y = pack2(a.z, a.w);
    o.z = pack2(b.x, b.y); o.w = pack2(b.z, b.w);
    ((uint4*)dst)[i] = o;
}

// ---------------------------------------------------------------------------
// Aggregation: wave-per-node, 4 nodes/block (256 thr), 4 feats/lane (uint2).
// ---------------------------------------------------------------------------
__global__ void agg_kernel(const unsigned short* __restrict__ Hin,
                           unsigned short* __restrict__ T,
                           const int* __restrict__ offs, const int* __restrict__ esrc,
                           const float* __restrict__ ew, const float* __restrict__ dinvp,
                           float* __restrict__ bnsum, float* __restrict__ bnsq) {
    int t = threadIdx.x;
    if (blockIdx.x == 0) { bnsum[t] = 0.f; bnsq[t] = 0.f; }   // blockDim==256
    int wv = t >> 6, lane = t & 63;
    int n = blockIdx.x * 4 + wv;          // grid = Nn/4 exact
    int o0 = offs[n], o1 = offs[n + 1];
    float dn = dinvp[n];
    uint2 u = *(const uint2*)&Hin[(size_t)n * Hdim + lane * 4];
    float a0, a1, a2, a3;
    unpack2(u.x, a0, a1); unpack2(u.y, a2, a3);
    a0 *= dn; a1 *= dn; a2 *= dn; a3 *= dn;
    for (int e = o0; e < o1; ++e) {
        int s = esrc[e];
        float w = ew[e];
        uint2 us = *(const uint2*)&Hin[(size_t)s * Hdim + lane * 4];
        float v0, v1, v2, v3;
        unpack2(us.x, v0, v1); unpack2(us.y, v2, v3);
        a0 += w * v0; a1 += w * v1; a2 += w * v2; a3 += w * v3;
    }
    uint2 o;
    o.x = pack2(dn * a0, dn * a1); o.y = pack2(dn * a2, dn * a3);
    *(uint2*)&T[(size_t)n * Hdim + lane * 4] = o;
}

// ---------------------------------------------------------------------------
// MFMA GEMM: C[M,256] = A[M,K] @ (Whi+Wlo)[K,256] + bias.
// A staged in double-buffered LDS (1 barrier/k-iter); B fragments read
// directly from L2 (weights are block-shared, stay resident).
// Epilogue: BN stats from acc, then coalesced C store via wave-private
// LDS transpose (32x72-stride pane per wave, two passes, no barriers).
// ---------------------------------------------------------------------------
__global__ __launch_bounds__(512) void gemm_mfma(
    const unsigned short* __restrict__ A, unsigned short* __restrict__ C,
    const unsigned short* __restrict__ Whi, const unsigned short* __restrict__ Wlo,
    const float* __restrict__ bias, int K, int nrows,
    float* __restrict__ bnsum, float* __restrict__ bnsq, int do_stats)
{
    // union: k-loop uses [0,10240) as A dbuf (2 x 128x40); epilogue uses
    // [0,18432) as 8 wave-private 32x72 transpose panes. 36 KB.
    __shared__ __align__(16) unsigned short smem[18432];
    __shared__ float lsum[256];
    __shared__ float lsq[256];

    const int t    = threadIdx.x;
    const int lane = t & 63, wid = t >> 6;
    const int ln   = lane & 15, quad = lane >> 4;
    const int r64  = (wid >> 2) * 64, c64 = (wid & 3) * 64;
    const int r0   = blockIdx.x * 128;

    if (t < 256) { lsum[t] = 0.f; lsq[t] = 0.f; }

    f32x4 acc[4][4];
#pragma unroll
    for (int i = 0; i < 4; ++i)
#pragma unroll
        for (int j = 0; j < 4; ++j) acc[i][j] = (f32x4){0.f, 0.f, 0.f, 0.f};

    const int srow = t >> 2, skq = t & 3;         // staging: 1 uint4/thread
    const bool srow_ok = (r0 + srow < nrows);
    const int nk = K >> 5;

    for (int kt = 0; kt < nk; ++kt) {
        const int k0 = kt << 5;
        unsigned short* Ab = &smem[(kt & 1) * 5120];
        uint4 g = make_uint4(0u, 0u, 0u, 0u);
        if (srow_ok) g = *(const uint4*)&A[(size_t)(r0 + srow) * K + k0 + skq * 8];
        *(uint4*)&Ab[srow * 40 + skq * 8] = g;
        __syncthreads();

        bf16x8 af[4], bh[4], bl[4];
#pragma unroll
        for (int ct = 0; ct < 4; ++ct) {          // B straight from L2
            size_t co = (size_t)(c64 + ct * 16 + ln) * K + k0 + quad * 8;
            bh[ct] = *(const bf16x8*)&Whi[co];
            bl[ct] = *(const bf16x8*)&Wlo[co];
        }
#pragma unroll
        for (int rt = 0; rt < 4; ++rt)
            af[rt] = *(const bf16x8*)&Ab[(r64 + rt * 16 + ln) * 40 + quad * 8];

#pragma unroll
        for (int rt = 0; rt < 4; ++rt)
#pragma unroll
            for (int ct = 0; ct < 4; ++ct)
                acc[rt][ct] = __builtin_amdgcn_mfma_f32_16x16x32_bf16(af[rt], bh[ct], acc[rt][ct], 0, 0, 0);
#pragma unroll
        for (int rt = 0; rt < 4; ++rt)
#pragma unroll
            for (int ct = 0; ct < 4; ++ct)
                acc[rt][ct] = __builtin_amdgcn_mfma_f32_16x16x32_bf16(af[rt], bl[ct], acc[rt][ct], 0, 0, 0);
    }
    __syncthreads();   // k-loop LDS reads done; smem free for transpose panes

    float bc[4];
#pragma unroll
    for (int ct = 0; ct < 4; ++ct) bc[ct] = bias[c64 + ct * 16 + ln];

    // BN stats straight from acc (C/D layout: col = lane&15, row = quad*4+v)
    if (do_stats) {
#pragma unroll
        for (int ct = 0; ct < 4; ++ct) {
            float s = 0.f, qq = 0.f;
#pragma unroll
            for (int rt = 0; rt < 4; ++rt)
#pragma unroll
                for (int v = 0; v < 4; ++v) {
                    int row = r0 + r64 + rt * 16 + quad * 4 + v;
                    if (row < nrows) {
                        float val = acc[rt][ct][v] + bc[ct];
                        s += val; qq += val * val;
                    }
                }
            s  += __shfl_xor(s, 16);  s  += __shfl_xor(s, 32);
            qq += __shfl_xor(qq, 16); qq += __shfl_xor(qq, 32);
            if (quad == 0) { atomicAdd(&lsum[c64 + ct * 16 + ln], s); atomicAdd(&lsq[c64 + ct * 16 + ln], qq); }
        }
    }

    // coalesced C store: wave-private 32-row x 72-stride pane, 2 passes
    unsigned short* Tt = &smem[wid * 2304];
    const int rr2 = lane & 31, jh = lane >> 5;
#pragma unroll
    for (int h = 0; h < 2; ++h) {
#pragma unroll
        for (int rr = 0; rr < 2; ++rr) {
            int rt = 2 * h + rr;
#pragma unroll
            for (int ct = 0; ct < 4; ++ct)
#pragma unroll
                for (int v = 0; v < 4; ++v)
                    Tt[(rr * 16 + quad * 4 + v) * 72 + ct * 16 + ln] = f2bf(acc[rt][ct][v] + bc[ct]);
        }
        __asm__ volatile("s_waitcnt lgkmcnt(0)" ::: "memory");
        int grow = r0 + r64 + h * 32 + rr2;
        if (grow < nrows) {
#pragma unroll
            for (int j = 0; j < 4; ++j) {
                uint4 v4 = *(const uint4*)&Tt[rr2 * 72 + jh * 32 + j * 8];
                *(uint4*)&C[(size_t)grow * 256 + c64 + jh * 32 + j * 8] = v4;
            }
        }
        __asm__ volatile("s_waitcnt lgkmcnt(0)" ::: "memory");
    }

    if (do_stats) {
        __syncthreads();
        if (t < 256) { atomicAdd(&bnsum[t], lsum[t]); atomicAdd(&bnsq[t], lsq[t]); }
    }
}

// ---------------------------------------------------------------------------
// Apply: H = relu(T*scale+shift) + 0.2*X (+ 0.7*H);  M (+)= w[l]*H
// BN finalize + res-softmax folded in.
// ---------------------------------------------------------------------------
__global__ void apply_kernel(const unsigned short* __restrict__ T,
                             const unsigned short* __restrict__ X,
                             unsigned short* __restrict__ Hb, unsigned short* __restrict__ M,
                             const float* __restrict__ bnsum, const float* __restrict__ bnsq,
                             const float* __restrict__ gamma, const float* __restrict__ beta,
                             const float* __restrict__ res_w, int layer) {
    __shared__ float sc[256], sh[256];
    int t = threadIdx.x;   // blockDim = 256
    {
        float mean = bnsum[t] * (1.0f / Nn);
        float var  = fmaxf(bnsq[t] * (1.0f / Nn) - mean * mean, 0.f);
        float rstd = rsqrtf(var + 1e-5f);
        float s = gamma[t] * rstd;
        sc[t] = s; sh[t] = beta[t] - mean * s;
    }
    float m0 = res_w[0];
#pragma unroll
    for (int i = 1; i < Lnum; ++i) m0 = fmaxf(m0, res_w[i]);
    float se = 0.f, wl = 0.f;
#pragma unroll
    for (int i = 0; i < Lnum; ++i) {
        float e = __expf(res_w[i] - m0);
        se += e;
        if (i == layer) wl = e;
    }
    float wi = wl / se;
    __syncthreads();

    int idx = blockIdx.x * blockDim.x + t;   // uint4 index, Nn*32 total
    int c8 = idx & 31;
    float scl[8], shl[8];
#pragma unroll
    for (int k = 0; k < 8; ++k) { scl[k] = sc[c8 * 8 + k]; shl[k] = sh[c8 * 8 + k]; }

    uint4 tv = ((const uint4*)T)[idx];
    uint4 xv = ((const uint4*)X)[idx];
    float tf[8], xf[8];
    unpack2(tv.x, tf[0], tf[1]); unpack2(tv.y, tf[2], tf[3]);
    unpack2(tv.z, tf[4], tf[5]); unpack2(tv.w, tf[6], tf[7]);
    unpack2(xv.x, xf[0], xf[1]); unpack2(xv.y, xf[2], xf[3]);
    unpack2(xv.z, xf[4], xf[5]); unpack2(xv.w, xf[6], xf[7]);

    float a[8];
#pragma unroll
    for (int k = 0; k < 8; ++k)
        a[k] = fmaxf(tf[k] * scl[k] + shl[k], 0.f) + 0.2f * xf[k];
    if (layer > 0) {
        uint4 hv = ((const uint4*)Hb)[idx];
        float hf[8];
        unpack2(hv.x, hf[0], hf[1]); unpack2(hv.y, hf[2], hf[3]);
        unpack2(hv.z, hf[4], hf[5]); unpack2(hv.w, hf[6], hf[7]);
#pragma unroll
        for (int k = 0; k < 8; ++k) a[k] += 0.7f * hf[k];
    }
    uint4 ho;
    ho.x = pack2(a[0], a[1]); ho.y = pack2(a[2], a[3]);
    ho.z = pack2(a[4], a[5]); ho.w = pack2(a[6], a[7]);
    ((uint4*)Hb)[idx] = ho;

    float m[8];
    if (layer == 0) {
#pragma unroll
        for (int k = 0; k < 8; ++k) m[k] = wi * a[k];
    } else {
        uint4 mv = ((const uint4*)M)[idx];
        float mf[8];
        unpack2(mv.x, mf[0], mf[1]); unpack2(mv.y, mf[2], mf[3]);
        unpack2(mv.z, mf[4], mf[5]); unpack2(mv.w, mf[6], mf[7]);
#pragma unroll
        for (int k = 0; k < 8; ++k) m[k] = mf[k] + wi * a[k];
    }
    uint4 mo;
    mo.x = pack2(m[0], m[1]); mo.y = pack2(m[2], m[3]);
    mo.z = pack2(m[4], m[5]); mo.w = pack2(m[6], m[7]);
    ((uint4*)M)[idx] = mo;
}

// ---------------------------------------------------------------------------
// Head via MFMA: logits[N,40] = M @ out_w + out_b, log_softmax rows.
// ---------------------------------------------------------------------------
__global__ __launch_bounds__(512) void head_mfma(const unsigned short* __restrict__ M,
                                                 const unsigned short* __restrict__ Whd,
                                                 const unsigned short* __restrict__ Wld,
                                                 const float* __restrict__ out_b,
                                                 float* __restrict__ out, int nrows) {
    __shared__ unsigned short At[128 * 40];   // 10 KB
    const int t    = threadIdx.x;
    const int lane = t & 63, wid = t >> 6;
    const int ln   = lane & 15, quad = lane >> 4;
    const int r0   = blockIdx.x * 128;

    f32x4 acc[3];
#pragma unroll
    for (int ct = 0; ct < 3; ++ct) acc[ct] = (f32x4){0.f, 0.f, 0.f, 0.f};

    for (int k0 = 0; k0 < 256; k0 += 32) {
        __syncthreads();
        {
            int row = t >> 2, kq = t & 3;
            uint4 g = make_uint4(0u, 0u, 0u, 0u);
            if (r0 + row < nrows)
                g = *(const uint4*)&M[(size_t)(r0 + row) * 256 + k0 + kq * 8];
            *(uint4*)&At[row * 40 + kq * 8] = g;
        }
        __syncthreads();
        bf16x8 af = *(const bf16x8*)&At[(wid * 16 + ln) * 40 + quad * 8];
#pragma unroll
        for (int ct = 0; ct < 3; ++ct) {
            int c = ct * 16 + ln;
            bf16x8 bh = *(const bf16x8*)&Whd[c * 256 + k0 + quad * 8];
            bf16x8 bl = *(const bf16x8*)&Wld[c * 256 + k0 + quad * 8];
            acc[ct] = __builtin_amdgcn_mfma_f32_16x16x32_bf16(af, bh, acc[ct], 0, 0, 0);
            acc[ct] = __builtin_amdgcn_mfma_f32_16x16x32_bf16(af, bl, acc[ct], 0, 0, 0);
        }
    }

    int   cc[3]; float bias[3];
#pragma unroll
    for (int ct = 0; ct < 3; ++ct) {
        cc[ct] = ct * 16 + ln;
        bias[ct] = (cc[ct] < Ncls) ? out_b[cc[ct]] : 0.f;
    }
#pragma unroll
    for (int v = 0; v < 4; ++v) {
        int row = r0 + wid * 16 + quad * 4 + v;
        float val[3];
#pragma unroll
        for (int ct = 0; ct < 3; ++ct) val[ct] = acc[ct][v] + bias[ct];
        float mx = -1e30f;
#pragma unroll
        for (int ct = 0; ct < 3; ++ct) if (cc[ct] < Ncls) mx = fmaxf(mx, val[ct]);
        mx = fmaxf(mx, __shfl_xor(mx, 1)); mx = fmaxf(mx, __shfl_xor(mx, 2));
        mx = fmaxf(mx, __shfl_xor(mx, 4)); mx = fmaxf(mx, __shfl_xor(mx, 8));
        float s = 0.f;
#pragma unroll
        for (int ct = 0; ct < 3; ++ct) if (cc[ct] < Ncls) s += __expf(val[ct] - mx);
        s += __shfl_xor(s, 1); s += __shfl_xor(s, 2);
        s += __shfl_xor(s, 4); s += __shfl_xor(s, 8);
        float lse = mx + __logf(s);
        if (row < nrows) {
            out[(size_t)row * Ncls + cc[0]] = val[0] - lse;
            out[(size_t)row * Ncls + cc[1]] = val[1] - lse;
            if (ln < 8) out[(size_t)row * Ncls + cc[2]] = val[2] - lse;
        }
    }
}

// ---------------------------------------------------------------------------
extern "C" void kernel_launch(void* const* d_in, const int* in_sizes, int n_in,
                              void* d_out, int out_size, void* d_ws, size_t ws_size,
                              hipStream_t stream)
{
    const float* x      = (const float*)d_in[0];
    const int*   ei     = (const int*)d_in[1];
    const float* w_in   = (const float*)d_in[2];
    const float* b_in   = (const float*)d_in[3];
    const float* conv_w = (const float*)d_in[4];
    const float* conv_b = (const float*)d_in[5];
    const float* gamma  = (const float*)d_in[6];
    const float* beta   = (const float*)d_in[7];
    const float* out_w  = (const float*)d_in[8];
    const float* out_b  = (const float*)d_in[9];
    const float* res_w  = (const float*)d_in[10];
    float* out = (float*)d_out;
    char* ws = (char*)d_ws;

    // workspace layout (total ~211 MB), 16B-aligned slots
    int*   cnt    = (int*)  (ws + 0);
    int*   cursor = (int*)  (ws + 400000);
    int*   offs   = (int*)  (ws + 800000);
    float* dinvp  = (float*)(ws + 1200016);
    int*   esrc   = (int*)  (ws + 1600016);
    float* ew     = (float*)(ws + 2800016);
    float* bnsum  = (float*)(ws + 4000016);
    float* bnsq   = (float*)(ws + 4001040);
    int*   iscan  = (int*)  (ws + 4002064);
    int*   btot   = (int*)  (ws + 4402064);
    int*   bpref  = (int*)  (ws + 4402576);
    unsigned short* Whi = (unsigned short*)(ws + 4403088);   // [L][256][256] bf16
    unsigned short* Wlo = (unsigned short*)(ws + 5189520);
    unsigned short* Fhi = (unsigned short*)(ws + 5975952);   // [256][128] bf16
    unsigned short* Flo = (unsigned short*)(ws + 6041488);
    unsigned short* Whd = (unsigned short*)(ws + 6107024);   // [48][256] bf16
    unsigned short* Wld = (unsigned short*)(ws + 6131600);
    unsigned short* X   = (unsigned short*)(ws + 6156176);   // N*H bf16 = 51.2 MB each
    unsigned short* Hb  = X  + (size_t)Nn * Hdim;
    unsigned short* T   = Hb + (size_t)Nn * Hdim;
    unsigned short* M   = T  + (size_t)Nn * Hdim;
    unsigned short* xbf = M;   // scratch alias: fc input, dead before M first written

    hipMemsetAsync(cnt, 0, 800000, stream);  // cnt + cursor

    count_edges<<<(Ee + 255) / 256, 256, 0, stream>>>(ei, cnt);
    scan_block<<<SCAN_B, 1024, 0, stream>>>(cnt, iscan, btot);
    scan_tops<<<1, 128, 0, stream>>>(btot, bpref);
    scan_final<<<SCAN_B, 1024, 0, stream>>>(cnt, iscan, bpref, offs, dinvp);
    fill_csr<<<(Ee + 255) / 256, 256, 0, stream>>>(ei, offs, cursor, dinvp, esrc, ew);

    prep_weights<<<1712, 256, 0, stream>>>(conv_w, w_in, out_w,
                                           Whi, Wlo, Fhi, Flo, Whd, Wld);
    cvt_bf16<<<(Nn * FIN / 8 + 255) / 256, 256, 0, stream>>>(x, xbf, Nn * FIN / 8);

    const int gblocks = (Nn + 127) / 128;   // 782
    gemm_mfma<<<gblocks, 512, 0, stream>>>(xbf, X, Fhi, Flo, b_in, FIN, Nn,
                                           nullptr, nullptr, 0);

    for (int i = 0; i < Lnum; ++i) {
        agg_kernel<<<Nn / 4, 256, 0, stream>>>(i == 0 ? X : Hb, T, offs, esrc, ew, dinvp,
                                               bnsum, bnsq);
        gemm_mfma<<<gblocks, 512, 0, stream>>>(T, T,
                                               Whi + (size_t)i * Hdim * Hdim,
                                               Wlo + (size_t)i * Hdim * Hdim,
                                               conv_b + (size_t)i * Hdim,
                                               Hdim, Nn, bnsum, bnsq, 1);
        apply_kernel<<<(Nn * 32) / 256, 256, 0, stream>>>(T, X, Hb, M,
                                                          bnsum, bnsq,
                                                          gamma + (size_t)i * Hdim,
                                                          beta + (size_t)i * Hdim,
                                                          res_w, i);
    }

    head_mfma<<<gblocks, 512, 0, stream>>>(M, Whd, Wld, out_b, out, Nn);
}

// Round 7
// 1271.349 us; speedup vs baseline: 1.2216x; 1.2216x over previous
//
#include <hip/hip_runtime.h>
#include <math.h>

// Problem constants (from reference)
#define Nn   100000
#define Ee   300000
#define FIN  128
#define Hdim 256
#define Ncls 40
#define Lnum 6
#define SCAN_B 98   // ceil(Nn/1024)

typedef __attribute__((ext_vector_type(8))) short bf16x8;
typedef __attribute__((ext_vector_type(4))) float f32x4;

// ---------------- bf16 helpers (storage bf16, compute fp32) ----------------
__device__ __forceinline__ float bf2f(unsigned int u16) {
    unsigned int x = u16 << 16;
    return __builtin_bit_cast(float, x);
}
__device__ __forceinline__ unsigned short f2bf(float f) {
    unsigned int x = __builtin_bit_cast(unsigned int, f);
    x = (x + 0x7FFFu + ((x >> 16) & 1u)) >> 16;   // round-nearest-even
    return (unsigned short)x;
}
__device__ __forceinline__ void unpack2(unsigned int u, float& lo, float& hi) {
    lo = __builtin_bit_cast(float, u << 16);
    hi = __builtin_bit_cast(float, u & 0xFFFF0000u);
}
__device__ __forceinline__ unsigned int pack2(float a, float b) {
    return (unsigned int)f2bf(a) | ((unsigned int)f2bf(b) << 16);
}

// ---------------------------------------------------------------------------
// Graph preprocessing
// ---------------------------------------------------------------------------
__global__ void count_edges(const int* __restrict__ ei, int* __restrict__ cnt) {
    int e = blockIdx.x * blockDim.x + threadIdx.x;
    if (e < Ee) atomicAdd(&cnt[ei[Ee + e]], 1);   // row 1 of edge_index = dst
}

__global__ void scan_block(const int* __restrict__ cnt, int* __restrict__ iscan,
                           int* __restrict__ btot) {
    __shared__ int buf[1024];
    int t = threadIdx.x;
    int g = blockIdx.x * 1024 + t;
    int v = (g < Nn) ? cnt[g] : 0;
    buf[t] = v; __syncthreads();
    for (int off = 1; off < 1024; off <<= 1) {
        int x = buf[t];
        int a = (t >= off) ? buf[t - off] : 0;
        __syncthreads();
        buf[t] = x + a;
        __syncthreads();
    }
    if (g < Nn) iscan[g] = buf[t];
    if (t == 1023) btot[blockIdx.x] = buf[1023];
}

__global__ void scan_tops(const int* __restrict__ btot, int* __restrict__ bpref) {
    __shared__ int b[128];
    int t = threadIdx.x;
    int v = (t < SCAN_B) ? btot[t] : 0;
    b[t] = v; __syncthreads();
    for (int off = 1; off < 128; off <<= 1) {
        int x = b[t];
        int a = (t >= off) ? b[t - off] : 0;
        __syncthreads();
        b[t] = x + a;
        __syncthreads();
    }
    if (t < SCAN_B) bpref[t] = b[t] - v;   // exclusive
}

__global__ void scan_final(const int* __restrict__ cnt, const int* __restrict__ iscan,
                           const int* __restrict__ bpref, int* __restrict__ offs,
                           float* __restrict__ dinvp) {
    int g = blockIdx.x * 1024 + threadIdx.x;
    if (g < Nn) {
        int c = cnt[g];
        offs[g] = bpref[blockIdx.x] + iscan[g] - c;
        dinvp[g] = rsqrtf((float)(c + 1));    // deg = in-deg + self-loop
    }
    if (g == 0) offs[Nn] = Ee;
}

__global__ void fill_csr(const int* __restrict__ ei, const int* __restrict__ offs,
                         int* __restrict__ cur, const float* __restrict__ dinvp,
                         int* __restrict__ esrc, float* __restrict__ ew) {
    int e = blockIdx.x * blockDim.x + threadIdx.x;
    if (e >= Ee) return;
    int s = ei[e], d = ei[Ee + e];
    int p = offs[d] + atomicAdd(&cur[d], 1);
    esrc[p] = s;
    ew[p] = dinvp[s];
}

// ---------------------------------------------------------------------------
// All weight prep in ONE dispatch (blockIdx ranges).
// conv/fc: bf16 hi only (accuracy budget per round-7 analysis).
// head: hi+lo (cheap, keeps final logits tight).
// ---------------------------------------------------------------------------
__global__ void prep_weights(const float* __restrict__ conv_w, const float* __restrict__ w_in,
                             const float* __restrict__ out_w,
                             unsigned short* __restrict__ Whi,
                             unsigned short* __restrict__ Fhi,
                             unsigned short* __restrict__ Whd, unsigned short* __restrict__ Wld) {
    int b = blockIdx.x, t = threadIdx.x;
    if (b < 1536) {
        int id = b * 256 + t;                    // [0, 393216)
        int l = id >> 16, k = (id >> 8) & 255, n = id & 255;
        Whi[l * 65536 + n * 256 + k] = f2bf(conv_w[id]);
    } else if (b < 1664) {
        int id = (b - 1536) * 256 + t;           // [0, 32768)
        int k = id >> 8, n = id & 255;
        Fhi[n * FIN + k] = f2bf(w_in[id]);
    } else {
        int id = (b - 1664) * 256 + t;           // [0, 12288)
        int c = id >> 8, k = id & 255;
        float w = (c < Ncls) ? out_w[k * Ncls + c] : 0.f;
        unsigned short hi = f2bf(w);
        unsigned short lo = f2bf(w - bf2f(hi));
        Whd[c * 256 + k] = hi;
        Wld[c * 256 + k] = lo;
    }
}

// x fp32 -> bf16 (8 elems/thread)
__global__ void cvt_bf16(const float* __restrict__ src, unsigned short* __restrict__ dst, int n8) {
    int i = blockIdx.x * blockDim.x + threadIdx.x;
    if (i >= n8) return;
    float4 a = ((const float4*)src)[i * 2];
    float4 b = ((const float4*)src)[i * 2 + 1];
    uint4 o;
    o.x = pack2(a.x, a.y); o.y = pack2(a.z, a.w);
    o.z = pack2(b.x, b.y); o.w = pack2(b.z, b.w);
    ((uint4*)dst)[i] = o;
}

// ---------------------------------------------------------------------------
// Aggregation: wave-per-node, 4 nodes/block (256 thr), 4 feats/lane (uint2).
// ---------------------------------------------------------------------------
__global__ void agg_kernel(const unsigned short* __restrict__ Hin,
                           unsigned short* __restrict__ T,
                           const int* __restrict__ offs, const int* __restrict__ esrc,
                           const float* __restrict__ ew, const float* __restrict__ dinvp,
                           float* __restrict__ bnsum, float* __restrict__ bnsq) {
    int t = threadIdx.x;
    if (blockIdx.x == 0) { bnsum[t] = 0.f; bnsq[t] = 0.f; }   // blockDim==256
    int wv = t >> 6, lane = t & 63;
    int n = blockIdx.x * 4 + wv;          // grid = Nn/4 exact
    int o0 = offs[n], o1 = offs[n + 1];
    float dn = dinvp[n];
    uint2 u = *(const uint2*)&Hin[(size_t)n * Hdim + lane * 4];
    float a0, a1, a2, a3;
    unpack2(u.x, a0, a1); unpack2(u.y, a2, a3);
    a0 *= dn; a1 *= dn; a2 *= dn; a3 *= dn;
    for (int e = o0; e < o1; ++e) {
        int s = esrc[e];
        float w = ew[e];
        uint2 us = *(const uint2*)&Hin[(size_t)s * Hdim + lane * 4];
        float v0, v1, v2, v3;
        unpack2(us.x, v0, v1); unpack2(us.y, v2, v3);
        a0 += w * v0; a1 += w * v1; a2 += w * v2; a3 += w * v3;
    }
    uint2 o;
    o.x = pack2(dn * a0, dn * a1); o.y = pack2(dn * a2, dn * a3);
    *(uint2*)&T[(size_t)n * Hdim + lane * 4] = o;
}

// ---------------------------------------------------------------------------
// MFMA GEMM: C[M,256] = A[M,K] @ W[K,256] + bias (bf16, fp32 accum;
// W transposed [256][K]). 128x256 block, 8 waves, 4x4 16x16x32 tiles.
// A+B staged in LDS (R5 structure — validated fast) with REGISTER PREFETCH
// of iter k+1's global loads overlapping iter k's MFMAs.
// Epilogue: BN stats from acc + coalesced C store via wave-private LDS
// transpose panes (validated R6: WRITE_SIZE 109 -> 55 MB).
// ---------------------------------------------------------------------------
__global__ __launch_bounds__(512) void gemm_mfma(
    const unsigned short* __restrict__ A, unsigned short* __restrict__ C,
    const unsigned short* __restrict__ W,
    const float* __restrict__ bias, int K, int nrows,
    float* __restrict__ bnsum, float* __restrict__ bnsq, int do_stats)
{
    // union: k-loop At[0,5120) + Bt[5120,15360); epilogue 8 panes x 2304. 36 KB.
    __shared__ __align__(16) unsigned short smem[18432];
    __shared__ float lsum[256];
    __shared__ float lsq[256];

    const int t    = threadIdx.x;
    const int lane = t & 63, wid = t >> 6;
    const int ln   = lane & 15, quad = lane >> 4;
    const int r64  = (wid >> 2) * 64, c64 = (wid & 3) * 64;
    const int r0   = blockIdx.x * 128;

    if (t < 256) { lsum[t] = 0.f; lsq[t] = 0.f; }

    unsigned short* At = smem;
    unsigned short* Bt = smem + 5120;

    f32x4 acc[4][4];
#pragma unroll
    for (int i = 0; i < 4; ++i)
#pragma unroll
        for (int j = 0; j < 4; ++j) acc[i][j] = (f32x4){0.f, 0.f, 0.f, 0.f};

    const int arow = t >> 2, akq = t & 3;     // A: 512 uint4, 1/thread
    const bool arow_ok = (r0 + arow < nrows);
    const int nk = K >> 5;

    // prefetch iter 0 into registers
    uint4 ga = make_uint4(0u, 0u, 0u, 0u);
    if (arow_ok) ga = *(const uint4*)&A[(size_t)(r0 + arow) * K + akq * 8];
    uint4 gb[2];
#pragma unroll
    for (int q = 0; q < 2; ++q) {             // B: 1024 uint4, 2/thread
        int idx = t + 512 * q, row = idx >> 2, kq = idx & 3;
        gb[q] = *(const uint4*)&W[(size_t)row * K + kq * 8];
    }

    for (int kt = 0; kt < nk; ++kt) {
        __syncthreads();                      // prev-iter frag reads done
        *(uint4*)&At[arow * 40 + akq * 8] = ga;
#pragma unroll
        for (int q = 0; q < 2; ++q) {
            int idx = t + 512 * q, row = idx >> 2, kq = idx & 3;
            *(uint4*)&Bt[row * 40 + kq * 8] = gb[q];
        }
        __syncthreads();
        if (kt + 1 < nk) {                    // prefetch next iter (overlaps MFMAs)
            int k0 = (kt + 1) << 5;
            ga = make_uint4(0u, 0u, 0u, 0u);
            if (arow_ok) ga = *(const uint4*)&A[(size_t)(r0 + arow) * K + k0 + akq * 8];
#pragma unroll
            for (int q = 0; q < 2; ++q) {
                int idx = t + 512 * q, row = idx >> 2, kq = idx & 3;
                gb[q] = *(const uint4*)&W[(size_t)row * K + k0 + kq * 8];
            }
        }
        bf16x8 af[4], bf[4];
#pragma unroll
        for (int rt = 0; rt < 4; ++rt)
            af[rt] = *(const bf16x8*)&At[(r64 + rt * 16 + ln) * 40 + quad * 8];
#pragma unroll
        for (int ct = 0; ct < 4; ++ct)
            bf[ct] = *(const bf16x8*)&Bt[(c64 + ct * 16 + ln) * 40 + quad * 8];
#pragma unroll
        for (int rt = 0; rt < 4; ++rt)
#pragma unroll
            for (int ct = 0; ct < 4; ++ct)
                acc[rt][ct] = __builtin_amdgcn_mfma_f32_16x16x32_bf16(af[rt], bf[ct], acc[rt][ct], 0, 0, 0);
    }
    __syncthreads();   // all k-loop LDS reads done; smem free for transpose panes

    float bc[4];
#pragma unroll
    for (int ct = 0; ct < 4; ++ct) bc[ct] = bias[c64 + ct * 16 + ln];

    // BN stats straight from acc (C/D layout: col = lane&15, row = quad*4+v)
    if (do_stats) {
#pragma unroll
        for (int ct = 0; ct < 4; ++ct) {
            float s = 0.f, qq = 0.f;
#pragma unroll
            for (int rt = 0; rt < 4; ++rt)
#pragma unroll
                for (int v = 0; v < 4; ++v) {
                    int row = r0 + r64 + rt * 16 + quad * 4 + v;
                    if (row < nrows) {
                        float val = acc[rt][ct][v] + bc[ct];
                        s += val; qq += val * val;
                    }
                }
            s  += __shfl_xor(s, 16);  s  += __shfl_xor(s, 32);
            qq += __shfl_xor(qq, 16); qq += __shfl_xor(qq, 32);
            if (quad == 0) { atomicAdd(&lsum[c64 + ct * 16 + ln], s); atomicAdd(&lsq[c64 + ct * 16 + ln], qq); }
        }
    }

    // coalesced C store: wave-private 32-row x 72-stride pane, 2 passes
    unsigned short* Tt = &smem[wid * 2304];
    const int rr2 = lane & 31, jh = lane >> 5;
#pragma unroll
    for (int h = 0; h < 2; ++h) {
#pragma unroll
        for (int rr = 0; rr < 2; ++rr) {
            int rt = 2 * h + rr;
#pragma unroll
            for (int ct = 0; ct < 4; ++ct)
#pragma unroll
                for (int v = 0; v < 4; ++v)
                    Tt[(rr * 16 + quad * 4 + v) * 72 + ct * 16 + ln] = f2bf(acc[rt][ct][v] + bc[ct]);
        }
        __asm__ volatile("s_waitcnt lgkmcnt(0)" ::: "memory");
        int grow = r0 + r64 + h * 32 + rr2;
        if (grow < nrows) {
#pragma unroll
            for (int j = 0; j < 4; ++j) {
                uint4 v4 = *(const uint4*)&Tt[rr2 * 72 + jh * 32 + j * 8];
                *(uint4*)&C[(size_t)grow * 256 + c64 + jh * 32 + j * 8] = v4;
            }
        }
        __asm__ volatile("s_waitcnt lgkmcnt(0)" ::: "memory");
    }

    if (do_stats) {
        __syncthreads();
        if (t < 256) { atomicAdd(&bnsum[t], lsum[t]); atomicAdd(&bnsq[t], lsq[t]); }
    }
}

// ---------------------------------------------------------------------------
// Apply: H = relu(T*scale+shift) + 0.2*X (+ 0.7*H);  M (+)= w[l]*H
// BN finalize + res-softmax folded in.
// ---------------------------------------------------------------------------
__global__ void apply_kernel(const unsigned short* __restrict__ T,
                             const unsigned short* __restrict__ X,
                             unsigned short* __restrict__ Hb, unsigned short* __restrict__ M,
                             const float* __restrict__ bnsum, const float* __restrict__ bnsq,
                             const float* __restrict__ gamma, const float* __restrict__ beta,
                             const float* __restrict__ res_w, int layer) {
    __shared__ float sc[256], sh[256];
    int t = threadIdx.x;   // blockDim = 256
    {
        float mean = bnsum[t] * (1.0f / Nn);
        float var  = fmaxf(bnsq[t] * (1.0f / Nn) - mean * mean, 0.f);
        float rstd = rsqrtf(var + 1e-5f);
        float s = gamma[t] * rstd;
        sc[t] = s; sh[t] = beta[t] - mean * s;
    }
    float m0 = res_w[0];
#pragma unroll
    for (int i = 1; i < Lnum; ++i) m0 = fmaxf(m0, res_w[i]);
    float se = 0.f, wl = 0.f;
#pragma unroll
    for (int i = 0; i < Lnum; ++i) {
        float e = __expf(res_w[i] - m0);
        se += e;
        if (i == layer) wl = e;
    }
    float wi = wl / se;
    __syncthreads();

    int idx = blockIdx.x * blockDim.x + t;   // uint4 index, Nn*32 total
    int c8 = idx & 31;
    float scl[8], shl[8];
#pragma unroll
    for (int k = 0; k < 8; ++k) { scl[k] = sc[c8 * 8 + k]; shl[k] = sh[c8 * 8 + k]; }

    uint4 tv = ((const uint4*)T)[idx];
    uint4 xv = ((const uint4*)X)[idx];
    float tf[8], xf[8];
    unpack2(tv.x, tf[0], tf[1]); unpack2(tv.y, tf[2], tf[3]);
    unpack2(tv.z, tf[4], tf[5]); unpack2(tv.w, tf[6], tf[7]);
    unpack2(xv.x, xf[0], xf[1]); unpack2(xv.y, xf[2], xf[3]);
    unpack2(xv.z, xf[4], xf[5]); unpack2(xv.w, xf[6], xf[7]);

    float a[8];
#pragma unroll
    for (int k = 0; k < 8; ++k)
        a[k] = fmaxf(tf[k] * scl[k] + shl[k], 0.f) + 0.2f * xf[k];
    if (layer > 0) {
        uint4 hv = ((const uint4*)Hb)[idx];
        float hf[8];
        unpack2(hv.x, hf[0], hf[1]); unpack2(hv.y, hf[2], hf[3]);
        unpack2(hv.z, hf[4], hf[5]); unpack2(hv.w, hf[6], hf[7]);
#pragma unroll
        for (int k = 0; k < 8; ++k) a[k] += 0.7f * hf[k];
    }
    uint4 ho;
    ho.x = pack2(a[0], a[1]); ho.y = pack2(a[2], a[3]);
    ho.z = pack2(a[4], a[5]); ho.w = pack2(a[6], a[7]);
    ((uint4*)Hb)[idx] = ho;

    float m[8];
    if (layer == 0) {
#pragma unroll
        for (int k = 0; k < 8; ++k) m[k] = wi * a[k];
    } else {
        uint4 mv = ((const uint4*)M)[idx];
        float mf[8];
        unpack2(mv.x, mf[0], mf[1]); unpack2(mv.y, mf[2], mf[3]);
        unpack2(mv.z, mf[4], mf[5]); unpack2(mv.w, mf[6], mf[7]);
#pragma unroll
        for (int k = 0; k < 8; ++k) m[k] = mf[k] + wi * a[k];
    }
    uint4 mo;
    mo.x = pack2(m[0], m[1]); mo.y = pack2(m[2], m[3]);
    mo.z = pack2(m[4], m[5]); mo.w = pack2(m[6], m[7]);
    ((uint4*)M)[idx] = mo;
}

// ---------------------------------------------------------------------------
// Head via MFMA: logits[N,40] = M @ out_w + out_b, log_softmax rows.
// ---------------------------------------------------------------------------
__global__ __launch_bounds__(512) void head_mfma(const unsigned short* __restrict__ M,
                                                 const unsigned short* __restrict__ Whd,
                                                 const unsigned short* __restrict__ Wld,
                                                 const float* __restrict__ out_b,
                                                 float* __restrict__ out, int nrows) {
    __shared__ unsigned short At[128 * 40];   // 10 KB
    const int t    = threadIdx.x;
    const int lane = t & 63, wid = t >> 6;
    const int ln   = lane & 15, quad = lane >> 4;
    const int r0   = blockIdx.x * 128;

    f32x4 acc[3];
#pragma unroll
    for (int ct = 0; ct < 3; ++ct) acc[ct] = (f32x4){0.f, 0.f, 0.f, 0.f};

    for (int k0 = 0; k0 < 256; k0 += 32) {
        __syncthreads();
        {
            int row = t >> 2, kq = t & 3;
            uint4 g = make_uint4(0u, 0u, 0u, 0u);
            if (r0 + row < nrows)
                g = *(const uint4*)&M[(size_t)(r0 + row) * 256 + k0 + kq * 8];
            *(uint4*)&At[row * 40 + kq * 8] = g;
        }
        __syncthreads();
        bf16x8 af = *(const bf16x8*)&At[(wid * 16 + ln) * 40 + quad * 8];
#pragma unroll
        for (int ct = 0; ct < 3; ++ct) {
            int c = ct * 16 + ln;
            bf16x8 bh = *(const bf16x8*)&Whd[c * 256 + k0 + quad * 8];
            bf16x8 bl = *(const bf16x8*)&Wld[c * 256 + k0 + quad * 8];
            acc[ct] = __builtin_amdgcn_mfma_f32_16x16x32_bf16(af, bh, acc[ct], 0, 0, 0);
            acc[ct] = __builtin_amdgcn_mfma_f32_16x16x32_bf16(af, bl, acc[ct], 0, 0, 0);
        }
    }

    int   cc[3]; float bias[3];
#pragma unroll
    for (int ct = 0; ct < 3; ++ct) {
        cc[ct] = ct * 16 + ln;
        bias[ct] = (cc[ct] < Ncls) ? out_b[cc[ct]] : 0.f;
    }
#pragma unroll
    for (int v = 0; v < 4; ++v) {
        int row = r0 + wid * 16 + quad * 4 + v;
        float val[3];
#pragma unroll
        for (int ct = 0; ct < 3; ++ct) val[ct] = acc[ct][v] + bias[ct];
        float mx = -1e30f;
#pragma unroll
        for (int ct = 0; ct < 3; ++ct) if (cc[ct] < Ncls) mx = fmaxf(mx, val[ct]);
        mx = fmaxf(mx, __shfl_xor(mx, 1)); mx = fmaxf(mx, __shfl_xor(mx, 2));
        mx = fmaxf(mx, __shfl_xor(mx, 4)); mx = fmaxf(mx, __shfl_xor(mx, 8));
        float s = 0.f;
#pragma unroll
        for (int ct = 0; ct < 3; ++ct) if (cc[ct] < Ncls) s += __expf(val[ct] - mx);
        s += __shfl_xor(s, 1); s += __shfl_xor(s, 2);
        s += __shfl_xor(s, 4); s += __shfl_xor(s, 8);
        float lse = mx + __logf(s);
        if (row < nrows) {
            out[(size_t)row * Ncls + cc[0]] = val[0] - lse;
            out[(size_t)row * Ncls + cc[1]] = val[1] - lse;
            if (ln < 8) out[(size_t)row * Ncls + cc[2]] = val[2] - lse;
        }
    }
}

// ---------------------------------------------------------------------------
extern "C" void kernel_launch(void* const* d_in, const int* in_sizes, int n_in,
                              void* d_out, int out_size, void* d_ws, size_t ws_size,
                              hipStream_t stream)
{
    const float* x      = (const float*)d_in[0];
    const int*   ei     = (const int*)d_in[1];
    const float* w_in   = (const float*)d_in[2];
    const float* b_in   = (const float*)d_in[3];
    const float* conv_w = (const float*)d_in[4];
    const float* conv_b = (const float*)d_in[5];
    const float* gamma  = (const float*)d_in[6];
    const float* beta   = (const float*)d_in[7];
    const float* out_w  = (const float*)d_in[8];
    const float* out_b  = (const float*)d_in[9];
    const float* res_w  = (const float*)d_in[10];
    float* out = (float*)d_out;
    char* ws = (char*)d_ws;

    // workspace layout (total ~211 MB), 16B-aligned slots
    int*   cnt    = (int*)  (ws + 0);
    int*   cursor = (int*)  (ws + 400000);
    int*   offs   = (int*)  (ws + 800000);
    float* dinvp  = (float*)(ws + 1200016);
    int*   esrc   = (int*)  (ws + 1600016);
    float* ew     = (float*)(ws + 2800016);
    float* bnsum  = (float*)(ws + 4000016);
    float* bnsq   = (float*)(ws + 4001040);
    int*   iscan  = (int*)  (ws + 4002064);
    int*   btot   = (int*)  (ws + 4402064);
    int*   bpref  = (int*)  (ws + 4402576);
    unsigned short* Whi = (unsigned short*)(ws + 4403088);   // [L][256][256] bf16
    unsigned short* Fhi = (unsigned short*)(ws + 5975952);   // [256][128] bf16
    unsigned short* Whd = (unsigned short*)(ws + 6107024);   // [48][256] bf16
    unsigned short* Wld = (unsigned short*)(ws + 6131600);
    unsigned short* X   = (unsigned short*)(ws + 6156176);   // N*H bf16 = 51.2 MB each
    unsigned short* Hb  = X  + (size_t)Nn * Hdim;
    unsigned short* T   = Hb + (size_t)Nn * Hdim;
    unsigned short* M   = T  + (size_t)Nn * Hdim;
    unsigned short* xbf = M;   // scratch alias: fc input, dead before M first written

    hipMemsetAsync(cnt, 0, 800000, stream);  // cnt + cursor

    count_edges<<<(Ee + 255) / 256, 256, 0, stream>>>(ei, cnt);
    scan_block<<<SCAN_B, 1024, 0, stream>>>(cnt, iscan, btot);
    scan_tops<<<1, 128, 0, stream>>>(btot, bpref);
    scan_final<<<SCAN_B, 1024, 0, stream>>>(cnt, iscan, bpref, offs, dinvp);
    fill_csr<<<(Ee + 255) / 256, 256, 0, stream>>>(ei, offs, cursor, dinvp, esrc, ew);

    prep_weights<<<1712, 256, 0, stream>>>(conv_w, w_in, out_w,
                                           Whi, Fhi, Whd, Wld);
    cvt_bf16<<<(Nn * FIN / 8 + 255) / 256, 256, 0, stream>>>(x, xbf, Nn * FIN / 8);

    const int gblocks = (Nn + 127) / 128;   // 782
    gemm_mfma<<<gblocks, 512, 0, stream>>>(xbf, X, Fhi, b_in, FIN, Nn,
                                           nullptr, nullptr, 0);

    for (int i = 0; i < Lnum; ++i) {
        agg_kernel<<<Nn / 4, 256, 0, stream>>>(i == 0 ? X : Hb, T, offs, esrc, ew, dinvp,
                                               bnsum, bnsq);
        gemm_mfma<<<gblocks, 512, 0, stream>>>(T, T,
                                               Whi + (size_t)i * Hdim * Hdim,
                                               conv_b + (size_t)i * Hdim,
                                               Hdim, Nn, bnsum, bnsq, 1);
        apply_kernel<<<(Nn * 32) / 256, 256, 0, stream>>>(T, X, Hb, M,
                                                          bnsum, bnsq,
                                                          gamma + (size_t)i * Hdim,
                                                          beta + (size_t)i * Hdim,
                                                          res_w, i);
    }

    head_mfma<<<gblocks, 512, 0, stream>>>(M, Whd, Wld, out_b, out, Nn);
}